// Round 8
// baseline (235.770 us; speedup 1.0000x reference)
//
#include <hip/hip_runtime.h>
#include <hip/hip_bf16.h>

// T6 tensor-product attention, MI355X gfx950.
// B=2 S=2048 D=1024 H=16 DK=64 QR=6 R=2.
// R14: TLP attack on the three non-flash worker kernels (pattern proven 3x: R10 gemm
//      retile, R11 flash split-K helped; R12 anti-TLP regressed).
//      - gemm3/gemm_out: 64x128 -> 32x128 tiles, 1024 blocks = 4 blocks/CU (16 waves/CU).
//      - combine_vt: 16 -> 8 tokens/block, 512 blocks = 2 blocks/CU (was 1!); P loads
//        vectorized to uint4 (range boundaries 96/480/32/160 all %8==0).
//      flash kept at R13 (43.6us: split-K groups + T14 prefetch + T5 setprio);
//      pack_wT kept at R13 (vectorized stores).

typedef __attribute__((ext_vector_type(8))) short short8;   // 8 bf16 = 4 VGPRs
typedef __attribute__((ext_vector_type(4))) float floatx4;  // 4 fp32 acc

#define MFMA16(a, b, c) __builtin_amdgcn_mfma_f32_16x16x32_bf16(a, b, c, 0, 0, 0)

__device__ __forceinline__ float b2f(short s) {
    unsigned int u = ((unsigned int)(unsigned short)s) << 16;
    float f; __builtin_memcpy(&f, &u, 4); return f;
}
__device__ __forceinline__ unsigned short bfbits(float x) {
    __hip_bfloat16 h = __float2bfloat16(x);
    unsigned short u; __builtin_memcpy(&u, &h, 2); return u;
}

// ---------------------------------------------------------------- pack all W^T into one contiguous
// bf16 region [2048 rows x 1024 cols], zero-padded, via LDS tile transpose.
// rows: [0,96)=AqT [96,480)=BqT [480,512)=0 | [512,544)=AkT [544,672)=BkT [672,768)=0 |
//       [768,800)=AvT [800,928)=BvT [928,1024)=0 | [1024,2048)=WoT
__device__ __forceinline__ float wsrc(int n, int k,
                                      const float* __restrict__ Aq, const float* __restrict__ Bq,
                                      const float* __restrict__ Ak, const float* __restrict__ Bk,
                                      const float* __restrict__ Av, const float* __restrict__ Bv,
                                      const float* __restrict__ Wo) {
    if (n < 96) return Aq[(size_t)k * 96 + n];
    if (n < 480) return Bq[(size_t)k * 384 + (n - 96)];
    if (n < 512) return 0.f;
    if (n < 544) return Ak[(size_t)k * 32 + (n - 512)];
    if (n < 672) return Bk[(size_t)k * 128 + (n - 544)];
    if (n < 768) return 0.f;
    if (n < 800) return Av[(size_t)k * 32 + (n - 768)];
    if (n < 928) return Bv[(size_t)k * 128 + (n - 800)];
    if (n < 1024) return 0.f;
    return Wo[(size_t)k * 1024 + (n - 1024)];
}

__global__ __launch_bounds__(256) void pack_wT_kernel(const float* __restrict__ Aq,
                                                      const float* __restrict__ Bq,
                                                      const float* __restrict__ Ak,
                                                      const float* __restrict__ Bk,
                                                      const float* __restrict__ Av,
                                                      const float* __restrict__ Bv,
                                                      const float* __restrict__ Wo,
                                                      __hip_bfloat16* __restrict__ outBase) {
    __shared__ float tile[64][65];
    int k0 = blockIdx.x * 64, n0 = blockIdx.y * 64;
    int tid = threadIdx.x;
#pragma unroll
    for (int p = 0; p < 16; ++p) {
        int idx = p * 256 + tid;
        int kl = idx >> 6, nl = idx & 63;
        tile[kl][nl] = wsrc(n0 + nl, k0 + kl, Aq, Bq, Ak, Bk, Av, Bv, Wo);
    }
    __syncthreads();
    // store phase: 4 k's per thread -> 8B ushort4 stores (16 lanes = 128B contiguous)
#pragma unroll
    for (int p = 0; p < 4; ++p) {
        int idx = p * 256 + tid;            // 0..1023
        int nl = idx >> 4, kq = (idx & 15) * 4;
        ushort4 o;
        o.x = bfbits(tile[kq][nl]);
        o.y = bfbits(tile[kq + 1][nl]);
        o.z = bfbits(tile[kq + 2][nl]);
        o.w = bfbits(tile[kq + 3][nl]);
        *(ushort4*)&outBase[(size_t)(n0 + nl) * 1024 + k0 + kq] = o;
    }
}

// ---------------------------------------------------------------- fused q/k/v projection GEMM
// 32x128 tiles, 1024 blocks (4 blocks/CU). A fp32 (inline cvt to bf16), C bf16.
// lin: XCD = lin&7; mi = (lin&7)+8*((lin>>3)&15) (0..127, XCD-affine m-strips);
// t = lin>>7 col-tile (4 q, 2 k, 2 v). 4 waves x 32 cols, acc[2][2].
__global__ __launch_bounds__(256) void gemm3_kernel(const float* __restrict__ q,
                                                    const float* __restrict__ k,
                                                    const float* __restrict__ v,
                                                    const __hip_bfloat16* __restrict__ WT,
                                                    __hip_bfloat16* __restrict__ Pq,
                                                    __hip_bfloat16* __restrict__ Pk,
                                                    __hip_bfloat16* __restrict__ Pv) {
    __shared__ __align__(16) __hip_bfloat16 As[32][72];
    __shared__ __align__(16) __hip_bfloat16 Bs[128][72];
    int lin = blockIdx.x;                         // 0..1023
    int t = lin >> 7;                             // 0..7
    int mi = (lin & 7) + (((lin >> 3) & 15) << 3);// 0..127
    int m0 = mi * 32;
    const float* A; __hip_bfloat16* C; int N, n0, wrow;
    if (t < 4)      { A = q; C = Pq; N = 512; n0 = t * 128;        wrow = t * 128; }
    else if (t < 6) { A = k; C = Pk; N = 256; n0 = (t - 4) * 128;  wrow = 512 + (t - 4) * 128; }
    else            { A = v; C = Pv; N = 256; n0 = (t - 6) * 128;  wrow = 768 + (t - 6) * 128; }
    int tid = threadIdx.x;
    int wave = tid >> 6, lane = tid & 63, quad = lane >> 4, l15 = lane & 15;
    floatx4 acc[2][2];
#pragma unroll
    for (int mt = 0; mt < 2; ++mt)
#pragma unroll
        for (int nt = 0; nt < 2; ++nt) acc[mt][nt] = (floatx4){0.f, 0.f, 0.f, 0.f};

    for (int k0 = 0; k0 < 1024; k0 += 64) {
#pragma unroll
        for (int pp = 0; pp < 2; ++pp) {          // A fp32 -> bf16 inline (32x64)
            int idx = pp * 256 + tid;             // 0..511
            int row = idx >> 4, c4 = (idx & 15) * 4;
            float4 av = *(const float4*)(A + (size_t)(m0 + row) * 1024 + k0 + c4);
            ushort4 bv;
            bv.x = bfbits(av.x); bv.y = bfbits(av.y); bv.z = bfbits(av.z); bv.w = bfbits(av.w);
            *(ushort4*)&As[row][c4] = bv;
        }
#pragma unroll
        for (int pp = 0; pp < 4; ++pp) {          // B packed bf16 (128x64)
            int idx = pp * 256 + tid;             // 0..1023
            int row = idx >> 3, c8 = (idx & 7) * 8;
            *(uint4*)&Bs[row][c8] = *(const uint4*)(WT + (size_t)(wrow + row) * 1024 + k0 + c8);
        }
        __syncthreads();
#pragma unroll
        for (int ks = 0; ks < 64; ks += 32) {
            short8 af[2], bf[2];
#pragma unroll
            for (int mt = 0; mt < 2; ++mt)
                af[mt] = *(const short8*)&As[mt * 16 + l15][ks + quad * 8];
#pragma unroll
            for (int nt = 0; nt < 2; ++nt)
                bf[nt] = *(const short8*)&Bs[wave * 32 + nt * 16 + l15][ks + quad * 8];
#pragma unroll
            for (int mt = 0; mt < 2; ++mt)
#pragma unroll
                for (int nt = 0; nt < 2; ++nt)
                    acc[mt][nt] = MFMA16(af[mt], bf[nt], acc[mt][nt]);
        }
        __syncthreads();
    }
#pragma unroll
    for (int mt = 0; mt < 2; ++mt)
#pragma unroll
        for (int nt = 0; nt < 2; ++nt)
#pragma unroll
            for (int r = 0; r < 4; ++r) {
                int row = m0 + mt * 16 + quad * 4 + r;
                int col = n0 + wave * 32 + nt * 16 + l15;
                C[(size_t)row * N + col] = __float2bfloat16(acc[mt][nt][r]);
            }
}

// ---------------------------------------------------------------- output GEMM: out = att @ WoT^T
// 32x128 tiles, 1024 blocks (4 blocks/CU). A bf16, C fp32. Same layout as gemm3.
__global__ __launch_bounds__(256) void gemm_out_kernel(const __hip_bfloat16* __restrict__ A,
                                                       const __hip_bfloat16* __restrict__ BT,
                                                       float* __restrict__ C) {
    __shared__ __align__(16) __hip_bfloat16 As[32][72];
    __shared__ __align__(16) __hip_bfloat16 Bs[128][72];
    int lin = blockIdx.x;                         // 0..1023
    int n0 = (lin >> 7) * 128;
    int mi = (lin & 7) + (((lin >> 3) & 15) << 3);// 0..127
    int m0 = mi * 32;
    int tid = threadIdx.x;
    int wave = tid >> 6, lane = tid & 63, quad = lane >> 4, l15 = lane & 15;
    floatx4 acc[2][2];
#pragma unroll
    for (int mt = 0; mt < 2; ++mt)
#pragma unroll
        for (int nt = 0; nt < 2; ++nt) acc[mt][nt] = (floatx4){0.f, 0.f, 0.f, 0.f};

    for (int k0 = 0; k0 < 1024; k0 += 64) {
        {                                          // A bf16 (32x64): 1 uint4 per thread
            int row = tid >> 3, c8 = (tid & 7) * 8;
            *(uint4*)&As[row][c8] = *(const uint4*)(A + (size_t)(m0 + row) * 1024 + k0 + c8);
        }
#pragma unroll
        for (int pp = 0; pp < 4; ++pp) {          // B bf16 (128x64)
            int idx = pp * 256 + tid;             // 0..1023
            int row = idx >> 3, c8 = (idx & 7) * 8;
            *(uint4*)&Bs[row][c8] = *(const uint4*)(BT + (size_t)(n0 + row) * 1024 + k0 + c8);
        }
        __syncthreads();
#pragma unroll
        for (int ks = 0; ks < 64; ks += 32) {
            short8 af[2], bf[2];
#pragma unroll
            for (int mt = 0; mt < 2; ++mt)
                af[mt] = *(const short8*)&As[mt * 16 + l15][ks + quad * 8];
#pragma unroll
            for (int nt = 0; nt < 2; ++nt)
                bf[nt] = *(const short8*)&Bs[wave * 32 + nt * 16 + l15][ks + quad * 8];
#pragma unroll
            for (int mt = 0; mt < 2; ++mt)
#pragma unroll
                for (int nt = 0; nt < 2; ++nt)
                    acc[mt][nt] = MFMA16(af[mt], bf[nt], acc[mt][nt]);
        }
        __syncthreads();
    }
#pragma unroll
    for (int mt = 0; mt < 2; ++mt)
#pragma unroll
        for (int nt = 0; nt < 2; ++nt)
#pragma unroll
            for (int r = 0; r < 4; ++r) {
                int row = m0 + mt * 16 + quad * 4 + r;
                int col = n0 + wave * 32 + nt * 16 + l15;
                C[(size_t)row * 1024 + col] = acc[mt][nt][r];
            }
}

// ---------------------------------------------------------------- fused combine(+RoPE) + V-transpose
// R14: block = 8 tokens -> 512 blocks (2 blocks/CU, was 1). P loads vectorized uint4
// (range boundaries 96/480 and 32/160 are %8==0, so chunks never straddle a split).
// qh folds log2(e)/768; vh folds 0.5. Padding cols (Pq 480.., Pk/Pv 160..) SKIPPED.
__global__ __launch_bounds__(256) void combine_vt_kernel(const __hip_bfloat16* __restrict__ Pq,
                                                         const __hip_bfloat16* __restrict__ Pk,
                                                         const __hip_bfloat16* __restrict__ Pv,
                                                         __hip_bfloat16* __restrict__ qh,
                                                         __hip_bfloat16* __restrict__ kh,
                                                         __hip_bfloat16* __restrict__ vT) {
    __shared__ __align__(16) __hip_bfloat16 LAq[8][96];
    __shared__ __align__(16) __hip_bfloat16 LAk[8][32];
    __shared__ __align__(16) __hip_bfloat16 LAv[8][32];
    __shared__ __align__(16) __hip_bfloat16 LBq[8][6][72];
    __shared__ __align__(16) __hip_bfloat16 LBk[8][2][72];
    __shared__ __align__(16) __hip_bfloat16 LBv[8][2][72];
    int tid = threadIdx.x;
    int token0 = blockIdx.x * 8;
    int b = token0 >> 11, s0 = token0 & 2047, bh0 = b * 16;

    // Pq: 8 tokens x 64 uint4-chunks = 512 chunks, 2 per thread
#pragma unroll
    for (int p = 0; p < 2; ++p) {
        int i = p * 256 + tid;              // 0..511
        int s = i >> 6, c8 = (i & 63) * 8;
        uint4 val = *(const uint4*)(Pq + (size_t)(token0 + s) * 512 + c8);
        if (c8 < 96) *(uint4*)&LAq[s][c8] = val;
        else if (c8 < 480) *(uint4*)&LBq[s][(c8 - 96) >> 6][(c8 - 96) & 63] = val;
    }
    // Pk/Pv: 8 tokens x 32 chunks = 256 chunks, 1 per thread
    {
        int s = tid >> 5, c8 = (tid & 31) * 8;
        uint4 vk = *(const uint4*)(Pk + (size_t)(token0 + s) * 256 + c8);
        uint4 vv = *(const uint4*)(Pv + (size_t)(token0 + s) * 256 + c8);
        if (c8 < 32) { *(uint4*)&LAk[s][c8] = vk; *(uint4*)&LAv[s][c8] = vv; }
        else if (c8 < 160) {
            *(uint4*)&LBk[s][(c8 - 32) >> 6][(c8 - 32) & 63] = vk;
            *(uint4*)&LBv[s][(c8 - 32) >> 6][(c8 - 32) & 63] = vv;
        }
    }
    __syncthreads();
    // RoPE on Bq (6 rows) + Bk (2 rows): 8 s x 8 rows x 32 pairs = 2048, 8 per thread
#pragma unroll
    for (int p = 0; p < 8; ++p) {
        int i = p * 256 + tid;
        int s = i >> 8, rr = (i >> 5) & 7, d = i & 31;
        float inv = __expf(-(float)d * 0.28782313662425576f);   // ln(10000)/32
        float rev = (float)(s0 + s) * inv * 0.15915494309189535f;
        rev -= floorf(rev);
        float sn = __builtin_amdgcn_sinf(rev);
        float cs = __builtin_amdgcn_cosf(rev);
        if (rr < 6) {
            float x1 = b2f(*(short*)&LBq[s][rr][d]), x2 = b2f(*(short*)&LBq[s][rr][d + 32]);
            LBq[s][rr][d] = __float2bfloat16(x1 * cs + x2 * sn);
            LBq[s][rr][d + 32] = __float2bfloat16(-x1 * sn + x2 * cs);
        } else {
            int r2 = rr - 6;
            float x1 = b2f(*(short*)&LBk[s][r2][d]), x2 = b2f(*(short*)&LBk[s][r2][d + 32]);
            LBk[s][r2][d] = __float2bfloat16(x1 * cs + x2 * sn);
            LBk[s][r2][d + 32] = __float2bfloat16(-x1 * sn + x2 * cs);
        }
    }
    __syncthreads();
    const float QSCALE = 1.4426950408889634f / 768.0f;  // log2(e)/(QR*RANK*DK)
    // qh/kh: thread = (s = tid>>5, h = (tid>>1)&15, dhalf = tid&1); 32 d's each
    {
        int s = tid >> 5, h = (tid >> 1) & 15, dh = tid & 1;
        float aq[6], ak0, ak1;
#pragma unroll
        for (int r = 0; r < 6; ++r) aq[r] = b2f(*(short*)&LAq[s][h * 6 + r]);
        ak0 = b2f(*(short*)&LAk[s][h * 2]);
        ak1 = b2f(*(short*)&LAk[s][h * 2 + 1]);
        size_t obase = ((size_t)(bh0 + h) * 2048 + s0 + s) * 64;
#pragma unroll
        for (int dq = 0; dq < 4; ++dq) {
            int dc = dh * 32 + dq * 8;
            float accq[8] = {0, 0, 0, 0, 0, 0, 0, 0};
#pragma unroll
            for (int r = 0; r < 6; ++r) {
                short8 bq = *(const short8*)&LBq[s][r][dc];
#pragma unroll
                for (int e = 0; e < 8; ++e) accq[e] += aq[r] * b2f(bq[e]);
            }
            short8 bk0 = *(const short8*)&LBk[s][0][dc];
            short8 bk1 = *(const short8*)&LBk[s][1][dc];
            ushort outq[8], outk[8];
#pragma unroll
            for (int e = 0; e < 8; ++e) {
                outq[e] = bfbits(accq[e] * QSCALE);
                outk[e] = bfbits(ak0 * b2f(bk0[e]) + ak1 * b2f(bk1[e]));
            }
            *(uint4*)((__hip_bfloat16*)qh + obase + dc) = *(uint4*)outq;
            *(uint4*)((__hip_bfloat16*)kh + obase + dc) = *(uint4*)outk;
        }
    }
    // vT: thread = (s = tid&7, dg = tid>>3); writes vT[bh][d][s0+s], d = dg*2+dd
    {
        int s = tid & 7, dg = tid >> 3;     // dg 0..31
#pragma unroll
        for (int h = 0; h < 16; ++h) {
            float a0 = b2f(*(short*)&LAv[s][h * 2]) * 0.5f;
            float a1 = b2f(*(short*)&LAv[s][h * 2 + 1]) * 0.5f;
#pragma unroll
            for (int dd = 0; dd < 2; ++dd) {
                int d = dg * 2 + dd;
                float val = a0 * b2f(*(short*)&LBv[s][0][d]) + a1 * b2f(*(short*)&LBv[s][1][d]);
                vT[((size_t)(bh0 + h) * 64 + d) * 2048 + s0 + s] = __float2bfloat16(val);
            }
        }
    }
}

// ---------------------------------------------------------------- causal flash attention (R13 = R11 + setprio)
// 512 blocks x 512 threads (8 waves). Split-K wave groups: waves 0-3 (grp 0) compute
// even k-tiles from LDS buf0, waves 4-7 (grp 1) odd k-tiles from buf1; within a group,
// wv = wave&3 owns q-strip wv*16. Static-max softmax => O/rs are pure k-sums, so group
// partials add exactly (lane-aligned) via LDS at pass end. Tiles staged in PAIRS:
// 2 barriers per 2 tiles. T14 prefetch (issue pair p+1 after post-write barrier).
// T5: s_setprio(1) around the MFMA clusters (groups run phase-shifted -> arbitrable).
// 2 complementary passes (qi = 31-t then t): uniform 17 pairs per block.
// grid (32,16) linearized -> XCD-affine bh (K/V ~2MB per XCD L2).
__global__ __launch_bounds__(512) void flash_kernel(const __hip_bfloat16* __restrict__ qh,
                                                    const __hip_bfloat16* __restrict__ kh,
                                                    const __hip_bfloat16* __restrict__ vT,
                                                    __hip_bfloat16* __restrict__ att) {
    int lin = blockIdx.x + (blockIdx.y << 5);           // 0..511
    int bh = ((lin & 7) << 2) | ((lin >> 3) & 3);       // XCD-affine head mapping
    int tpair = lin >> 5;                               // 0..15
    int tid = threadIdx.x;
    int wave = tid >> 6, lane = tid & 63, quad = lane >> 4, l15 = lane & 15;
    int grp = wave >> 2, wv = wave & 3;
    __shared__ __align__(16) __hip_bfloat16 Ks[2][64][72];    // K[buf][kidx][d]
    __shared__ __align__(16) __hip_bfloat16 Vts[2][64][72];   // V^T[buf][d][kidx]
    float* cb = (float*)&Ks[0][0][0];   // combine buffer: 4*64*17 f32 = 17408B <= 18432B

    int row = tid >> 3, col = (tid & 7) * 8;            // staging: 512 thr cover 64x64 x4 arrays
    const size_t khb = (size_t)bh * 2048 * 64;
    const size_t vtb = (size_t)bh * 64 * 2048;
    uint4 sk0, sk1, sv0, sv1;
#define FL_ISSUE(P)                                                                  \
    {                                                                                \
        int k0_ = (P) * 128;                                                         \
        sk0 = *(const uint4*)(kh + khb + (size_t)(k0_ + row) * 64 + col);            \
        sk1 = *(const uint4*)(kh + khb + (size_t)(k0_ + 64 + row) * 64 + col);       \
        sv0 = *(const uint4*)(vT + vtb + (size_t)row * 2048 + k0_ + col);            \
        sv1 = *(const uint4*)(vT + vtb + (size_t)row * 2048 + k0_ + 64 + col);       \
    }

    for (int pass = 0; pass < 2; ++pass) {
        int qi = pass ? tpair : (31 - tpair);           // heavy pass first
        int q0 = qi * 64;
        int npairs = (qi + 2) >> 1;                     // ceil((qi+1)/2)
        const __hip_bfloat16* qrow =
            qh + ((size_t)bh * 2048 + q0 + wv * 16 + l15) * 64 + quad * 8;
        short8 aq0 = *(const short8*)(qrow);
        short8 aq1 = *(const short8*)(qrow + 32);

        floatx4 o[4];
#pragma unroll
        for (int nt = 0; nt < 4; ++nt) o[nt] = (floatx4){0.f, 0.f, 0.f, 0.f};
        float rs = 0.f;                 // scalar partial row-sum for q = wv*16 + l15
        int qloc = wv * 16 + l15;

        FL_ISSUE(0);
        for (int p = 0; p < npairs; ++p) {
            __syncthreads();            // all waves done reading previous buffers / cb
            *(uint4*)&Ks[0][row][col] = sk0;
            *(uint4*)&Ks[1][row][col] = sk1;
            *(uint4*)&Vts[0][row][col] = sv0;
            *(uint4*)&Vts[1][row][col] = sv1;
            __syncthreads();
            if (p + 1 < npairs) FL_ISSUE(p + 1);   // prefetch next pair during compute

            int mytile = 2 * p + grp;
            if (mytile <= qi) {         // wave-uniform predicate
                // S^T = K @ Q^T : lane holds S^T[k = nt*16+quad*4+r][q = l15]
                floatx4 s[4];
#pragma unroll
                for (int nt = 0; nt < 4; ++nt) s[nt] = (floatx4){0.f, 0.f, 0.f, 0.f};
                __builtin_amdgcn_s_setprio(1);
#pragma unroll
                for (int nt = 0; nt < 4; ++nt) {
                    short8 bk0 = *(const short8*)&Ks[grp][nt * 16 + l15][quad * 8];
                    short8 bk1 = *(const short8*)&Ks[grp][nt * 16 + l15][32 + quad * 8];
                    s[nt] = MFMA16(bk0, aq0, s[nt]);
                    s[nt] = MFMA16(bk1, aq1, s[nt]);
                }
                __builtin_amdgcn_s_setprio(0);
                if (mytile == qi) {  // causal mask on diagonal tile
#pragma unroll
                    for (int nt = 0; nt < 4; ++nt) {
                        int kbase = nt * 16 + quad * 4;
#pragma unroll
                        for (int r = 0; r < 4; ++r)
                            if (kbase + r > qloc) s[nt][r] = -__builtin_inff();
                    }
                }
                float pv[4][4];
#pragma unroll
                for (int nt = 0; nt < 4; ++nt)
#pragma unroll
                    for (int r = 0; r < 4; ++r) {
                        pv[nt][r] = exp2f(s[nt][r]);
                        rs += pv[nt][r];
                    }
                union { ushort u[8]; short8 v; } p0, p1;
#pragma unroll
                for (int r = 0; r < 4; ++r) {
                    p0.u[r]     = bfbits(pv[0][r]);
                    p0.u[4 + r] = bfbits(pv[1][r]);
                    p1.u[r]     = bfbits(pv[2][r]);
                    p1.u[4 + r] = bfbits(pv[3][r]);
                }
                // O^T += V^T @ P^T with slot-permuted V reads (4x b64 per d-block)
                __builtin_amdgcn_s_setprio(1);
#pragma unroll
                for (int nt = 0; nt < 4; ++nt) {
                    int vr = nt * 16 + l15;
                    union { ushort4 h[2]; short8 v; } x0, x1;
                    x0.h[0] = *(const ushort4*)&Vts[grp][vr][quad * 4];
                    x0.h[1] = *(const ushort4*)&Vts[grp][vr][16 + quad * 4];
                    x1.h[0] = *(const ushort4*)&Vts[grp][vr][32 + quad * 4];
                    x1.h[1] = *(const ushort4*)&Vts[grp][vr][48 + quad * 4];
                    o[nt] = MFMA16(x0.v, p0.v, o[nt]);
                    o[nt] = MFMA16(x1.v, p1.v, o[nt]);
                }
                __builtin_amdgcn_s_setprio(0);
            }
        }
        // cross-group combine: grp1 partials -> LDS, grp0 adds (lanes own same (q,d))
        __syncthreads();                // grp0's last compute done before cb overwrite
        int cbase = (wv * 64 + lane) * 17;
        if (grp == 1) {
#pragma unroll
            for (int nt = 0; nt < 4; ++nt)
#pragma unroll
                for (int r = 0; r < 4; ++r) cb[cbase + nt * 4 + r] = o[nt][r];
            cb[cbase + 16] = rs;
        }
        __syncthreads();
        if (grp == 0) {
#pragma unroll
            for (int nt = 0; nt < 4; ++nt)
#pragma unroll
                for (int r = 0; r < 4; ++r) o[nt][r] += cb[cbase + nt * 4 + r];
            rs += cb[cbase + 16];
            // full row-sum: reduce across the 4 quads holding q = l15
            rs += __shfl_xor(rs, 16, 64);
            rs += __shfl_xor(rs, 32, 64);
            float inv = 1.0f / rs;
            // epilogue: att[b][q][h*64+d], d = nt*16 + quad*4 + r -> 8B stores
            int b = bh >> 4, h = bh & 15;
            size_t obase = ((size_t)b * 2048 + q0 + wv * 16 + l15) * 1024 + h * 64 + quad * 4;
#pragma unroll
            for (int nt = 0; nt < 4; ++nt) {
                ushort ow[4];
#pragma unroll
                for (int r = 0; r < 4; ++r) ow[r] = bfbits(o[nt][r] * inv);
                *(ushort4*)((__hip_bfloat16*)att + obase + nt * 16) = *(ushort4*)ow;
            }
        }
    }
#undef FL_ISSUE
}

// ---------------------------------------------------------------- launch
extern "C" void kernel_launch(void* const* d_in, const int* in_sizes, int n_in,
                              void* d_out, int out_size, void* d_ws, size_t ws_size,
                              hipStream_t stream) {
    const float* q = (const float*)d_in[0];
    const float* k = (const float*)d_in[1];
    const float* v = (const float*)d_in[2];
    // d_in[3] = causal mask (ignored; computed analytically)
    const float* W_Aq = (const float*)d_in[4];
    const float* W_Ak = (const float*)d_in[5];
    const float* W_Av = (const float*)d_in[6];
    const float* W_Bq = (const float*)d_in[7];
    const float* W_Bk = (const float*)d_in[8];
    const float* W_Bv = (const float*)d_in[9];
    const float* Wo = (const float*)d_in[10];
    float* out = (float*)d_out;

    char* w = (char*)d_ws;
    __hip_bfloat16* qh  = (__hip_bfloat16*)(w + 0);          // [32][2048][64] 8.4 MB
    __hip_bfloat16* kh  = (__hip_bfloat16*)(w + 8388608);    // [32][2048][64]
    __hip_bfloat16* vT  = (__hip_bfloat16*)(w + 16777216);   // [32][64][2048]
    __hip_bfloat16* WT  = (__hip_bfloat16*)(w + 25165824);   // [2048][1024] packed bf16
    __hip_bfloat16* WoT = WT + (size_t)1024 * 1024;          // rows 1024..2047
    __hip_bfloat16* Pq  = (__hip_bfloat16*)(w + 29360128);   // [4096][512] bf16
    __hip_bfloat16* Pk  = (__hip_bfloat16*)(w + 33554432);   // [4096][256]
    __hip_bfloat16* Pv  = (__hip_bfloat16*)(w + 35651584);   // [4096][256]
    __hip_bfloat16* att = (__hip_bfloat16*)(w + 37748736);   // [4096][1024] bf16

    pack_wT_kernel<<<dim3(16, 32), 256, 0, stream>>>(W_Aq, W_Bq, W_Ak, W_Bk, W_Av, W_Bv, Wo, WT);
    gemm3_kernel<<<1024, 256, 0, stream>>>(q, k, v, WT, Pq, Pk, Pv);
    combine_vt_kernel<<<512, 256, 0, stream>>>(Pq, Pk, Pv, qh, kh, vT);
    flash_kernel<<<dim3(32, 16), 512, 0, stream>>>(qh, kh, vT, att);
    gemm_out_kernel<<<1024, 256, 0, stream>>>(att, WoT, out);
}

// Round 10
// 228.136 us; speedup vs baseline: 1.0335x; 1.0335x over previous
//
#include <hip/hip_runtime.h>
#include <hip/hip_bf16.h>

// T6 tensor-product attention, MI355X gfx950.
// B=2 S=2048 D=1024 H=16 DK=64 QR=6 R=2.
// R16 == R15 resubmit (R15 bench died on container acquisition, not on the kernel;
//      same infra failure mode as R8->R9, which ran clean on resubmit).
// R15: (1) non-flash kernels at R13 exactly (R14's 32x128 retile + 8-token combine
//      cost +9us: staging overhead scales with block count; 64x128 @ 2 blocks/CU is
//      the sweet spot). (2) flash: grid 512 -> 1024 blocks (one q-tile pass per block,
//      32 bh x 32 qi, heavy-first). Resources allow 4 blocks/CU (LDS 36.9KB x4 = 147
//      <= 160KB, VGPR 48) but the 512-grid capped at 2 -> occ 34%. Inner structure
//      unchanged from R13 (split-K wave groups, pair staging, T14 prefetch, T5 setprio).

typedef __attribute__((ext_vector_type(8))) short short8;   // 8 bf16 = 4 VGPRs
typedef __attribute__((ext_vector_type(4))) float floatx4;  // 4 fp32 acc

#define MFMA16(a, b, c) __builtin_amdgcn_mfma_f32_16x16x32_bf16(a, b, c, 0, 0, 0)

__device__ __forceinline__ float b2f(short s) {
    unsigned int u = ((unsigned int)(unsigned short)s) << 16;
    float f; __builtin_memcpy(&f, &u, 4); return f;
}
__device__ __forceinline__ unsigned short bfbits(float x) {
    __hip_bfloat16 h = __float2bfloat16(x);
    unsigned short u; __builtin_memcpy(&u, &h, 2); return u;
}

// ---------------------------------------------------------------- pack all W^T into one contiguous
// bf16 region [2048 rows x 1024 cols], zero-padded, via LDS tile transpose.
// rows: [0,96)=AqT [96,480)=BqT [480,512)=0 | [512,544)=AkT [544,672)=BkT [672,768)=0 |
//       [768,800)=AvT [800,928)=BvT [928,1024)=0 | [1024,2048)=WoT
__device__ __forceinline__ float wsrc(int n, int k,
                                      const float* __restrict__ Aq, const float* __restrict__ Bq,
                                      const float* __restrict__ Ak, const float* __restrict__ Bk,
                                      const float* __restrict__ Av, const float* __restrict__ Bv,
                                      const float* __restrict__ Wo) {
    if (n < 96) return Aq[(size_t)k * 96 + n];
    if (n < 480) return Bq[(size_t)k * 384 + (n - 96)];
    if (n < 512) return 0.f;
    if (n < 544) return Ak[(size_t)k * 32 + (n - 512)];
    if (n < 672) return Bk[(size_t)k * 128 + (n - 544)];
    if (n < 768) return 0.f;
    if (n < 800) return Av[(size_t)k * 32 + (n - 768)];
    if (n < 928) return Bv[(size_t)k * 128 + (n - 800)];
    if (n < 1024) return 0.f;
    return Wo[(size_t)k * 1024 + (n - 1024)];
}

__global__ __launch_bounds__(256) void pack_wT_kernel(const float* __restrict__ Aq,
                                                      const float* __restrict__ Bq,
                                                      const float* __restrict__ Ak,
                                                      const float* __restrict__ Bk,
                                                      const float* __restrict__ Av,
                                                      const float* __restrict__ Bv,
                                                      const float* __restrict__ Wo,
                                                      __hip_bfloat16* __restrict__ outBase) {
    __shared__ float tile[64][65];
    int k0 = blockIdx.x * 64, n0 = blockIdx.y * 64;
    int tid = threadIdx.x;
#pragma unroll
    for (int p = 0; p < 16; ++p) {
        int idx = p * 256 + tid;
        int kl = idx >> 6, nl = idx & 63;
        tile[kl][nl] = wsrc(n0 + nl, k0 + kl, Aq, Bq, Ak, Bk, Av, Bv, Wo);
    }
    __syncthreads();
    // store phase: 4 k's per thread -> 8B ushort4 stores (16 lanes = 128B contiguous)
#pragma unroll
    for (int p = 0; p < 4; ++p) {
        int idx = p * 256 + tid;            // 0..1023
        int nl = idx >> 4, kq = (idx & 15) * 4;
        ushort4 o;
        o.x = bfbits(tile[kq][nl]);
        o.y = bfbits(tile[kq + 1][nl]);
        o.z = bfbits(tile[kq + 2][nl]);
        o.w = bfbits(tile[kq + 3][nl]);
        *(ushort4*)&outBase[(size_t)(n0 + nl) * 1024 + k0 + kq] = o;
    }
}

// ---------------------------------------------------------------- fused q/k/v projection GEMM
// 64x128 tiles, 512 blocks (2 blocks/CU). A fp32 (inline cvt to bf16), C bf16.
// lin: mi = (lin&7)+((lin>>6)<<3) m-strip (XCD-affine), t = (lin>>3)&7 col-tile (4q,2k,2v).
// 4 waves = 1m x 4n: wave covers all 64 rows x 32-col strip, acc[4][2].
__global__ __launch_bounds__(256) void gemm3_kernel(const float* __restrict__ q,
                                                    const float* __restrict__ k,
                                                    const float* __restrict__ v,
                                                    const __hip_bfloat16* __restrict__ WT,
                                                    __hip_bfloat16* __restrict__ Pq,
                                                    __hip_bfloat16* __restrict__ Pk,
                                                    __hip_bfloat16* __restrict__ Pv) {
    __shared__ __align__(16) __hip_bfloat16 As[64][72];
    __shared__ __align__(16) __hip_bfloat16 Bs[128][72];
    int lin = blockIdx.x;                         // 0..511
    int t = (lin >> 3) & 7;
    int mi = (lin & 7) + ((lin >> 6) << 3);       // 0..63
    int m0 = mi * 64;
    const float* A; __hip_bfloat16* C; int N, n0, wrow;
    if (t < 4)      { A = q; C = Pq; N = 512; n0 = t * 128;        wrow = t * 128; }
    else if (t < 6) { A = k; C = Pk; N = 256; n0 = (t - 4) * 128;  wrow = 512 + (t - 4) * 128; }
    else            { A = v; C = Pv; N = 256; n0 = (t - 6) * 128;  wrow = 768 + (t - 6) * 128; }
    int tid = threadIdx.x;
    int wave = tid >> 6, lane = tid & 63, quad = lane >> 4, l15 = lane & 15;
    floatx4 acc[4][2];
#pragma unroll
    for (int mt = 0; mt < 4; ++mt)
#pragma unroll
        for (int nt = 0; nt < 2; ++nt) acc[mt][nt] = (floatx4){0.f, 0.f, 0.f, 0.f};

    for (int k0 = 0; k0 < 1024; k0 += 64) {
#pragma unroll
        for (int pp = 0; pp < 4; ++pp) {          // A fp32 -> bf16 inline (64x64)
            int idx = pp * 256 + tid;             // 0..1023
            int row = idx >> 4, c4 = (idx & 15) * 4;
            float4 av = *(const float4*)(A + (size_t)(m0 + row) * 1024 + k0 + c4);
            ushort4 bv;
            bv.x = bfbits(av.x); bv.y = bfbits(av.y); bv.z = bfbits(av.z); bv.w = bfbits(av.w);
            *(ushort4*)&As[row][c4] = bv;
        }
#pragma unroll
        for (int pp = 0; pp < 4; ++pp) {          // B packed bf16 (128x64)
            int idx = pp * 256 + tid;             // 0..1023
            int row = idx >> 3, c8 = (idx & 7) * 8;
            *(uint4*)&Bs[row][c8] = *(const uint4*)(WT + (size_t)(wrow + row) * 1024 + k0 + c8);
        }
        __syncthreads();
#pragma unroll
        for (int ks = 0; ks < 64; ks += 32) {
            short8 af[4], bf[2];
#pragma unroll
            for (int mt = 0; mt < 4; ++mt)
                af[mt] = *(const short8*)&As[mt * 16 + l15][ks + quad * 8];
#pragma unroll
            for (int nt = 0; nt < 2; ++nt)
                bf[nt] = *(const short8*)&Bs[wave * 32 + nt * 16 + l15][ks + quad * 8];
#pragma unroll
            for (int mt = 0; mt < 4; ++mt)
#pragma unroll
                for (int nt = 0; nt < 2; ++nt)
                    acc[mt][nt] = MFMA16(af[mt], bf[nt], acc[mt][nt]);
        }
        __syncthreads();
    }
#pragma unroll
    for (int mt = 0; mt < 4; ++mt)
#pragma unroll
        for (int nt = 0; nt < 2; ++nt)
#pragma unroll
            for (int r = 0; r < 4; ++r) {
                int row = m0 + mt * 16 + quad * 4 + r;
                int col = n0 + wave * 32 + nt * 16 + l15;
                C[(size_t)row * N + col] = __float2bfloat16(acc[mt][nt][r]);
            }
}

// ---------------------------------------------------------------- output GEMM: out = att @ WoT^T
// 64x128 tiles, 512 blocks (2 blocks/CU). A bf16, C fp32. Same wave layout as gemm3.
__global__ __launch_bounds__(256) void gemm_out_kernel(const __hip_bfloat16* __restrict__ A,
                                                       const __hip_bfloat16* __restrict__ BT,
                                                       float* __restrict__ C) {
    __shared__ __align__(16) __hip_bfloat16 As[64][72];
    __shared__ __align__(16) __hip_bfloat16 Bs[128][72];
    int lin = blockIdx.x;                         // 0..511
    int n0 = ((lin >> 3) & 7) * 128;
    int mi = (lin & 7) + ((lin >> 6) << 3);       // 0..63
    int m0 = mi * 64;
    int tid = threadIdx.x;
    int wave = tid >> 6, lane = tid & 63, quad = lane >> 4, l15 = lane & 15;
    floatx4 acc[4][2];
#pragma unroll
    for (int mt = 0; mt < 4; ++mt)
#pragma unroll
        for (int nt = 0; nt < 2; ++nt) acc[mt][nt] = (floatx4){0.f, 0.f, 0.f, 0.f};

    for (int k0 = 0; k0 < 1024; k0 += 64) {
#pragma unroll
        for (int pp = 0; pp < 2; ++pp) {          // A bf16 (64x64)
            int idx = pp * 256 + tid;             // 0..511
            int row = idx >> 3, c8 = (idx & 7) * 8;
            *(uint4*)&As[row][c8] = *(const uint4*)(A + (size_t)(m0 + row) * 1024 + k0 + c8);
        }
#pragma unroll
        for (int pp = 0; pp < 4; ++pp) {          // B bf16 (128x64)
            int idx = pp * 256 + tid;             // 0..1023
            int row = idx >> 3, c8 = (idx & 7) * 8;
            *(uint4*)&Bs[row][c8] = *(const uint4*)(BT + (size_t)(n0 + row) * 1024 + k0 + c8);
        }
        __syncthreads();
#pragma unroll
        for (int ks = 0; ks < 64; ks += 32) {
            short8 af[4], bf[2];
#pragma unroll
            for (int mt = 0; mt < 4; ++mt)
                af[mt] = *(const short8*)&As[mt * 16 + l15][ks + quad * 8];
#pragma unroll
            for (int nt = 0; nt < 2; ++nt)
                bf[nt] = *(const short8*)&Bs[wave * 32 + nt * 16 + l15][ks + quad * 8];
#pragma unroll
            for (int mt = 0; mt < 4; ++mt)
#pragma unroll
                for (int nt = 0; nt < 2; ++nt)
                    acc[mt][nt] = MFMA16(af[mt], bf[nt], acc[mt][nt]);
        }
        __syncthreads();
    }
#pragma unroll
    for (int mt = 0; mt < 4; ++mt)
#pragma unroll
        for (int nt = 0; nt < 2; ++nt)
#pragma unroll
            for (int r = 0; r < 4; ++r) {
                int row = m0 + mt * 16 + quad * 4 + r;
                int col = n0 + wave * 32 + nt * 16 + l15;
                C[(size_t)row * 1024 + col] = acc[mt][nt][r];
            }
}

// ---------------------------------------------------------------- fused combine(+RoPE) + V-transpose
// Block = 16 tokens. Reads bf16 P once, writes qh/kh (token-major) and vT (d-major) directly.
// qh folds log2(e)/768; vh folds 0.5. Padding columns (Pq 480.., Pk/Pv 160..) are SKIPPED.
__global__ __launch_bounds__(256) void combine_vt_kernel(const __hip_bfloat16* __restrict__ Pq,
                                                         const __hip_bfloat16* __restrict__ Pk,
                                                         const __hip_bfloat16* __restrict__ Pv,
                                                         __hip_bfloat16* __restrict__ qh,
                                                         __hip_bfloat16* __restrict__ kh,
                                                         __hip_bfloat16* __restrict__ vT) {
    __shared__ __align__(16) __hip_bfloat16 LAq[16][96];
    __shared__ __align__(16) __hip_bfloat16 LAk[16][32];
    __shared__ __align__(16) __hip_bfloat16 LAv[16][32];
    __shared__ __align__(16) __hip_bfloat16 LBq[16][6][72];
    __shared__ __align__(16) __hip_bfloat16 LBk[16][2][72];
    __shared__ __align__(16) __hip_bfloat16 LBv[16][2][72];
    int tid = threadIdx.x;
    int token0 = blockIdx.x * 16;
    int b = token0 >> 11, s0 = token0 & 2047, bh0 = b * 16;

    for (int i = tid; i < 16 * 512; i += 256) {
        int s = i >> 9, c = i & 511;
        __hip_bfloat16 val = Pq[(size_t)(token0 + s) * 512 + c];
        if (c < 96) LAq[s][c] = val;
        else if (c < 480) LBq[s][(c - 96) >> 6][(c - 96) & 63] = val;  // skip pad cols 480..511
    }
    for (int i = tid; i < 16 * 256; i += 256) {
        int s = i >> 8, c = i & 255;
        __hip_bfloat16 vk = Pk[(size_t)(token0 + s) * 256 + c];
        __hip_bfloat16 vv = Pv[(size_t)(token0 + s) * 256 + c];
        if (c < 32) { LAk[s][c] = vk; LAv[s][c] = vv; }
        else if (c < 160) {                                            // skip pad cols 160..255
            LBk[s][(c - 32) >> 6][(c - 32) & 63] = vk;
            LBv[s][(c - 32) >> 6][(c - 32) & 63] = vv;
        }
    }
    __syncthreads();
    // RoPE on Bq (6 rows) + Bk (2 rows): 16 s x 8 rows x 32 pairs
    for (int i = tid; i < 4096; i += 256) {
        int s = i >> 8, rr = (i >> 5) & 7, d = i & 31;
        float inv = __expf(-(float)d * 0.28782313662425576f);   // ln(10000)/32
        float rev = (float)(s0 + s) * inv * 0.15915494309189535f;
        rev -= floorf(rev);
        float sn = __builtin_amdgcn_sinf(rev);
        float cs = __builtin_amdgcn_cosf(rev);
        if (rr < 6) {
            float x1 = b2f(*(short*)&LBq[s][rr][d]), x2 = b2f(*(short*)&LBq[s][rr][d + 32]);
            LBq[s][rr][d] = __float2bfloat16(x1 * cs + x2 * sn);
            LBq[s][rr][d + 32] = __float2bfloat16(-x1 * sn + x2 * cs);
        } else {
            int r2 = rr - 6;
            float x1 = b2f(*(short*)&LBk[s][r2][d]), x2 = b2f(*(short*)&LBk[s][r2][d + 32]);
            LBk[s][r2][d] = __float2bfloat16(x1 * cs + x2 * sn);
            LBk[s][r2][d + 32] = __float2bfloat16(-x1 * sn + x2 * cs);
        }
    }
    __syncthreads();
    const float QSCALE = 1.4426950408889634f / 768.0f;  // log2(e)/(QR*RANK*DK)
    // qh/kh: thread = (s, h); 64 d's each, 16B-chunk stores
    {
        int s = tid >> 4, h = tid & 15;
        float aq[6], ak0, ak1;
#pragma unroll
        for (int r = 0; r < 6; ++r) aq[r] = b2f(*(short*)&LAq[s][h * 6 + r]);
        ak0 = b2f(*(short*)&LAk[s][h * 2]);
        ak1 = b2f(*(short*)&LAk[s][h * 2 + 1]);
        size_t obase = ((size_t)(bh0 + h) * 2048 + s0 + s) * 64;
#pragma unroll
        for (int dc = 0; dc < 64; dc += 8) {
            float accq[8] = {0, 0, 0, 0, 0, 0, 0, 0};
#pragma unroll
            for (int r = 0; r < 6; ++r) {
                short8 bq = *(const short8*)&LBq[s][r][dc];
#pragma unroll
                for (int e = 0; e < 8; ++e) accq[e] += aq[r] * b2f(bq[e]);
            }
            short8 bk0 = *(const short8*)&LBk[s][0][dc];
            short8 bk1 = *(const short8*)&LBk[s][1][dc];
            ushort outq[8], outk[8];
#pragma unroll
            for (int e = 0; e < 8; ++e) {
                outq[e] = bfbits(accq[e] * QSCALE);
                outk[e] = bfbits(ak0 * b2f(bk0[e]) + ak1 * b2f(bk1[e]));
            }
            *(uint4*)((__hip_bfloat16*)qh + obase + dc) = *(uint4*)outq;
            *(uint4*)((__hip_bfloat16*)kh + obase + dc) = *(uint4*)outk;
        }
    }
    // vT: thread = (s = tid&15, dg = tid>>4); writes vT[bh][d][s0+s]
    {
        int s = tid & 15, dg = tid >> 4;
#pragma unroll
        for (int h = 0; h < 16; ++h) {
            float a0 = b2f(*(short*)&LAv[s][h * 2]) * 0.5f;
            float a1 = b2f(*(short*)&LAv[s][h * 2 + 1]) * 0.5f;
#pragma unroll
            for (int dd = 0; dd < 4; ++dd) {
                int d = dg * 4 + dd;
                float val = a0 * b2f(*(short*)&LBv[s][0][d]) + a1 * b2f(*(short*)&LBv[s][1][d]);
                vT[((size_t)(bh0 + h) * 64 + d) * 2048 + s0 + s] = __float2bfloat16(val);
            }
        }
    }
}

// ---------------------------------------------------------------- causal flash attention (R15)
// 1024 blocks x 512 threads: one q-tile pass per block (32 bh x 32 qi), heavy-first.
// 4 blocks/CU now fit (LDS 36.9KB x4 = 147KB, VGPR 48) -> up to 32 waves/CU.
// Split-K wave groups: waves 0-3 even k-tiles (buf0), waves 4-7 odd (buf1); wv owns
// q-strip wv*16. Static-max softmax => O/rs pure k-sums; group partials add exactly.
// Pair staging (2 barriers / 2 tiles), T14 prefetch, T5 setprio around MFMA clusters.
// grid (32,32) linearized -> XCD-affine bh (K/V ~2MB per XCD L2).
__global__ __launch_bounds__(512) void flash_kernel(const __hip_bfloat16* __restrict__ qh,
                                                    const __hip_bfloat16* __restrict__ kh,
                                                    const __hip_bfloat16* __restrict__ vT,
                                                    __hip_bfloat16* __restrict__ att) {
    int lin = blockIdx.x + (blockIdx.y << 5);           // 0..1023
    int bh = ((lin & 7) << 2) | ((lin >> 3) & 3);       // XCD-affine head mapping
    int qi = 31 - (lin >> 5);                           // heavy first
    int tid = threadIdx.x;
    int wave = tid >> 6, lane = tid & 63, quad = lane >> 4, l15 = lane & 15;
    int grp = wave >> 2, wv = wave & 3;
    __shared__ __align__(16) __hip_bfloat16 Ks[2][64][72];    // K[buf][kidx][d]
    __shared__ __align__(16) __hip_bfloat16 Vts[2][64][72];   // V^T[buf][d][kidx]
    float* cb = (float*)&Ks[0][0][0];   // combine buffer: 4*64*17 f32 = 17408B <= 18432B

    int row = tid >> 3, col = (tid & 7) * 8;            // staging: 512 thr cover 64x64 x4 arrays
    const size_t khb = (size_t)bh * 2048 * 64;
    const size_t vtb = (size_t)bh * 64 * 2048;
    uint4 sk0, sk1, sv0, sv1;
#define FL_ISSUE(P)                                                                  \
    {                                                                                \
        int k0_ = (P) * 128;                                                         \
        sk0 = *(const uint4*)(kh + khb + (size_t)(k0_ + row) * 64 + col);            \
        sk1 = *(const uint4*)(kh + khb + (size_t)(k0_ + 64 + row) * 64 + col);       \
        sv0 = *(const uint4*)(vT + vtb + (size_t)row * 2048 + k0_ + col);            \
        sv1 = *(const uint4*)(vT + vtb + (size_t)row * 2048 + k0_ + 64 + col);       \
    }

    int q0 = qi * 64;
    int npairs = (qi + 2) >> 1;                         // ceil((qi+1)/2)
    const __hip_bfloat16* qrow =
        qh + ((size_t)bh * 2048 + q0 + wv * 16 + l15) * 64 + quad * 8;
    short8 aq0 = *(const short8*)(qrow);
    short8 aq1 = *(const short8*)(qrow + 32);

    floatx4 o[4];
#pragma unroll
    for (int nt = 0; nt < 4; ++nt) o[nt] = (floatx4){0.f, 0.f, 0.f, 0.f};
    float rs = 0.f;                     // scalar partial row-sum for q = wv*16 + l15
    int qloc = wv * 16 + l15;

    FL_ISSUE(0);
    for (int p = 0; p < npairs; ++p) {
        __syncthreads();                // all waves done reading previous buffers
        *(uint4*)&Ks[0][row][col] = sk0;
        *(uint4*)&Ks[1][row][col] = sk1;
        *(uint4*)&Vts[0][row][col] = sv0;
        *(uint4*)&Vts[1][row][col] = sv1;
        __syncthreads();
        if (p + 1 < npairs) FL_ISSUE(p + 1);   // prefetch next pair during compute

        int mytile = 2 * p + grp;
        if (mytile <= qi) {             // wave-uniform predicate
            // S^T = K @ Q^T : lane holds S^T[k = nt*16+quad*4+r][q = l15]
            floatx4 s[4];
#pragma unroll
            for (int nt = 0; nt < 4; ++nt) s[nt] = (floatx4){0.f, 0.f, 0.f, 0.f};
            __builtin_amdgcn_s_setprio(1);
#pragma unroll
            for (int nt = 0; nt < 4; ++nt) {
                short8 bk0 = *(const short8*)&Ks[grp][nt * 16 + l15][quad * 8];
                short8 bk1 = *(const short8*)&Ks[grp][nt * 16 + l15][32 + quad * 8];
                s[nt] = MFMA16(bk0, aq0, s[nt]);
                s[nt] = MFMA16(bk1, aq1, s[nt]);
            }
            __builtin_amdgcn_s_setprio(0);
            if (mytile == qi) {  // causal mask on diagonal tile
#pragma unroll
                for (int nt = 0; nt < 4; ++nt) {
                    int kbase = nt * 16 + quad * 4;
#pragma unroll
                    for (int r = 0; r < 4; ++r)
                        if (kbase + r > qloc) s[nt][r] = -__builtin_inff();
                }
            }
            float pv[4][4];
#pragma unroll
            for (int nt = 0; nt < 4; ++nt)
#pragma unroll
                for (int r = 0; r < 4; ++r) {
                    pv[nt][r] = exp2f(s[nt][r]);
                    rs += pv[nt][r];
                }
            union { ushort u[8]; short8 v; } p0, p1;
#pragma unroll
            for (int r = 0; r < 4; ++r) {
                p0.u[r]     = bfbits(pv[0][r]);
                p0.u[4 + r] = bfbits(pv[1][r]);
                p1.u[r]     = bfbits(pv[2][r]);
                p1.u[4 + r] = bfbits(pv[3][r]);
            }
            // O^T += V^T @ P^T with slot-permuted V reads (4x b64 per d-block)
            __builtin_amdgcn_s_setprio(1);
#pragma unroll
            for (int nt = 0; nt < 4; ++nt) {
                int vr = nt * 16 + l15;
                union { ushort4 h[2]; short8 v; } x0, x1;
                x0.h[0] = *(const ushort4*)&Vts[grp][vr][quad * 4];
                x0.h[1] = *(const ushort4*)&Vts[grp][vr][16 + quad * 4];
                x1.h[0] = *(const ushort4*)&Vts[grp][vr][32 + quad * 4];
                x1.h[1] = *(const ushort4*)&Vts[grp][vr][48 + quad * 4];
                o[nt] = MFMA16(x0.v, p0.v, o[nt]);
                o[nt] = MFMA16(x1.v, p1.v, o[nt]);
            }
            __builtin_amdgcn_s_setprio(0);
        }
    }
    // cross-group combine: grp1 partials -> LDS, grp0 adds (lanes own same (q,d))
    __syncthreads();                    // grp0's last compute done before cb overwrite
    int cbase = (wv * 64 + lane) * 17;
    if (grp == 1) {
#pragma unroll
        for (int nt = 0; nt < 4; ++nt)
#pragma unroll
            for (int r = 0; r < 4; ++r) cb[cbase + nt * 4 + r] = o[nt][r];
        cb[cbase + 16] = rs;
    }
    __syncthreads();
    if (grp == 0) {
#pragma unroll
        for (int nt = 0; nt < 4; ++nt)
#pragma unroll
            for (int r = 0; r < 4; ++r) o[nt][r] += cb[cbase + nt * 4 + r];
        rs += cb[cbase + 16];
        // full row-sum: reduce across the 4 quads holding q = l15
        rs += __shfl_xor(rs, 16, 64);
        rs += __shfl_xor(rs, 32, 64);
        float inv = 1.0f / rs;
        // epilogue: att[b][q][h*64+d], d = nt*16 + quad*4 + r -> 8B stores
        int b = bh >> 4, h = bh & 15;
        size_t obase = ((size_t)b * 2048 + q0 + wv * 16 + l15) * 1024 + h * 64 + quad * 4;
#pragma unroll
        for (int nt = 0; nt < 4; ++nt) {
            ushort ow[4];
#pragma unroll
            for (int r = 0; r < 4; ++r) ow[r] = bfbits(o[nt][r] * inv);
            *(ushort4*)((__hip_bfloat16*)att + obase + nt * 16) = *(ushort4*)ow;
        }
    }
#undef FL_ISSUE
}

// ---------------------------------------------------------------- launch
extern "C" void kernel_launch(void* const* d_in, const int* in_sizes, int n_in,
                              void* d_out, int out_size, void* d_ws, size_t ws_size,
                              hipStream_t stream) {
    const float* q = (const float*)d_in[0];
    const float* k = (const float*)d_in[1];
    const float* v = (const float*)d_in[2];
    // d_in[3] = causal mask (ignored; computed analytically)
    const float* W_Aq = (const float*)d_in[4];
    const float* W_Ak = (const float*)d_in[5];
    const float* W_Av = (const float*)d_in[6];
    const float* W_Bq = (const float*)d_in[7];
    const float* W_Bk = (const float*)d_in[8];
    const float* W_Bv = (const float*)d_in[9];
    const float* Wo = (const float*)d_in[10];
    float* out = (float*)d_out;

    char* w = (char*)d_ws;
    __hip_bfloat16* qh  = (__hip_bfloat16*)(w + 0);          // [32][2048][64] 8.4 MB
    __hip_bfloat16* kh  = (__hip_bfloat16*)(w + 8388608);    // [32][2048][64]
    __hip_bfloat16* vT  = (__hip_bfloat16*)(w + 16777216);   // [32][64][2048]
    __hip_bfloat16* WT  = (__hip_bfloat16*)(w + 25165824);   // [2048][1024] packed bf16
    __hip_bfloat16* WoT = WT + (size_t)1024 * 1024;          // rows 1024..2047
    __hip_bfloat16* Pq  = (__hip_bfloat16*)(w + 29360128);   // [4096][512] bf16
    __hip_bfloat16* Pk  = (__hip_bfloat16*)(w + 33554432);   // [4096][256]
    __hip_bfloat16* Pv  = (__hip_bfloat16*)(w + 35651584);   // [4096][256]
    __hip_bfloat16* att = (__hip_bfloat16*)(w + 37748736);   // [4096][1024] bf16

    pack_wT_kernel<<<dim3(16, 32), 256, 0, stream>>>(W_Aq, W_Bq, W_Ak, W_Bk, W_Av, W_Bv, Wo, WT);
    gemm3_kernel<<<512, 256, 0, stream>>>(q, k, v, WT, Pq, Pk, Pv);
    combine_vt_kernel<<<256, 256, 0, stream>>>(Pq, Pk, Pv, qh, kh, vT);
    flash_kernel<<<dim3(32, 32), 512, 0, stream>>>(qh, kh, vT, att);
    gemm_out_kernel<<<512, 256, 0, stream>>>(att, WoT, out);
}

// Round 11
// 214.499 us; speedup vs baseline: 1.0992x; 1.0636x over previous
//
#include <hip/hip_runtime.h>
#include <hip/hip_bf16.h>

// T6 tensor-product attention, MI355X gfx950.
// B=2 S=2048 D=1024 H=16 DK=64 QR=6 R=2.
// R17: R16 falsified the flash grid-cap theory (1024 blocks -> occupancy STILL 34%,
//      dur 44.7 vs 43.6): flash is at a structural floor ~44us; reverted to R13's
//      512-block version. This round isolates the ONE R14 change never attributed:
//      combine_vt at 1 block/CU (the R9 gemm_out sin). combine = R14's 8-token/
//      512-block/uint4 version; everything else byte-identical to R13 (227.05 best).
//      If total drops ~10us, combine was latency-bound; if it rises, R14's combine
//      was the regressor and we pin 16-token permanently.

typedef __attribute__((ext_vector_type(8))) short short8;   // 8 bf16 = 4 VGPRs
typedef __attribute__((ext_vector_type(4))) float floatx4;  // 4 fp32 acc

#define MFMA16(a, b, c) __builtin_amdgcn_mfma_f32_16x16x32_bf16(a, b, c, 0, 0, 0)

__device__ __forceinline__ float b2f(short s) {
    unsigned int u = ((unsigned int)(unsigned short)s) << 16;
    float f; __builtin_memcpy(&f, &u, 4); return f;
}
__device__ __forceinline__ unsigned short bfbits(float x) {
    __hip_bfloat16 h = __float2bfloat16(x);
    unsigned short u; __builtin_memcpy(&u, &h, 2); return u;
}

// ---------------------------------------------------------------- pack all W^T into one contiguous
// bf16 region [2048 rows x 1024 cols], zero-padded, via LDS tile transpose.
// rows: [0,96)=AqT [96,480)=BqT [480,512)=0 | [512,544)=AkT [544,672)=BkT [672,768)=0 |
//       [768,800)=AvT [800,928)=BvT [928,1024)=0 | [1024,2048)=WoT
__device__ __forceinline__ float wsrc(int n, int k,
                                      const float* __restrict__ Aq, const float* __restrict__ Bq,
                                      const float* __restrict__ Ak, const float* __restrict__ Bk,
                                      const float* __restrict__ Av, const float* __restrict__ Bv,
                                      const float* __restrict__ Wo) {
    if (n < 96) return Aq[(size_t)k * 96 + n];
    if (n < 480) return Bq[(size_t)k * 384 + (n - 96)];
    if (n < 512) return 0.f;
    if (n < 544) return Ak[(size_t)k * 32 + (n - 512)];
    if (n < 672) return Bk[(size_t)k * 128 + (n - 544)];
    if (n < 768) return 0.f;
    if (n < 800) return Av[(size_t)k * 32 + (n - 768)];
    if (n < 928) return Bv[(size_t)k * 128 + (n - 800)];
    if (n < 1024) return 0.f;
    return Wo[(size_t)k * 1024 + (n - 1024)];
}

__global__ __launch_bounds__(256) void pack_wT_kernel(const float* __restrict__ Aq,
                                                      const float* __restrict__ Bq,
                                                      const float* __restrict__ Ak,
                                                      const float* __restrict__ Bk,
                                                      const float* __restrict__ Av,
                                                      const float* __restrict__ Bv,
                                                      const float* __restrict__ Wo,
                                                      __hip_bfloat16* __restrict__ outBase) {
    __shared__ float tile[64][65];
    int k0 = blockIdx.x * 64, n0 = blockIdx.y * 64;
    int tid = threadIdx.x;
#pragma unroll
    for (int p = 0; p < 16; ++p) {
        int idx = p * 256 + tid;
        int kl = idx >> 6, nl = idx & 63;
        tile[kl][nl] = wsrc(n0 + nl, k0 + kl, Aq, Bq, Ak, Bk, Av, Bv, Wo);
    }
    __syncthreads();
    // store phase: 4 k's per thread -> 8B ushort4 stores (16 lanes = 128B contiguous)
#pragma unroll
    for (int p = 0; p < 4; ++p) {
        int idx = p * 256 + tid;            // 0..1023
        int nl = idx >> 4, kq = (idx & 15) * 4;
        ushort4 o;
        o.x = bfbits(tile[kq][nl]);
        o.y = bfbits(tile[kq + 1][nl]);
        o.z = bfbits(tile[kq + 2][nl]);
        o.w = bfbits(tile[kq + 3][nl]);
        *(ushort4*)&outBase[(size_t)(n0 + nl) * 1024 + k0 + kq] = o;
    }
}

// ---------------------------------------------------------------- fused q/k/v projection GEMM
// 64x128 tiles, 512 blocks (2 blocks/CU). A fp32 (inline cvt to bf16), C bf16.
// lin: mi = (lin&7)+((lin>>6)<<3) m-strip (XCD-affine), t = (lin>>3)&7 col-tile (4q,2k,2v).
// 4 waves = 1m x 4n: wave covers all 64 rows x 32-col strip, acc[4][2].
__global__ __launch_bounds__(256) void gemm3_kernel(const float* __restrict__ q,
                                                    const float* __restrict__ k,
                                                    const float* __restrict__ v,
                                                    const __hip_bfloat16* __restrict__ WT,
                                                    __hip_bfloat16* __restrict__ Pq,
                                                    __hip_bfloat16* __restrict__ Pk,
                                                    __hip_bfloat16* __restrict__ Pv) {
    __shared__ __align__(16) __hip_bfloat16 As[64][72];
    __shared__ __align__(16) __hip_bfloat16 Bs[128][72];
    int lin = blockIdx.x;                         // 0..511
    int t = (lin >> 3) & 7;
    int mi = (lin & 7) + ((lin >> 6) << 3);       // 0..63
    int m0 = mi * 64;
    const float* A; __hip_bfloat16* C; int N, n0, wrow;
    if (t < 4)      { A = q; C = Pq; N = 512; n0 = t * 128;        wrow = t * 128; }
    else if (t < 6) { A = k; C = Pk; N = 256; n0 = (t - 4) * 128;  wrow = 512 + (t - 4) * 128; }
    else            { A = v; C = Pv; N = 256; n0 = (t - 6) * 128;  wrow = 768 + (t - 6) * 128; }
    int tid = threadIdx.x;
    int wave = tid >> 6, lane = tid & 63, quad = lane >> 4, l15 = lane & 15;
    floatx4 acc[4][2];
#pragma unroll
    for (int mt = 0; mt < 4; ++mt)
#pragma unroll
        for (int nt = 0; nt < 2; ++nt) acc[mt][nt] = (floatx4){0.f, 0.f, 0.f, 0.f};

    for (int k0 = 0; k0 < 1024; k0 += 64) {
#pragma unroll
        for (int pp = 0; pp < 4; ++pp) {          // A fp32 -> bf16 inline (64x64)
            int idx = pp * 256 + tid;             // 0..1023
            int row = idx >> 4, c4 = (idx & 15) * 4;
            float4 av = *(const float4*)(A + (size_t)(m0 + row) * 1024 + k0 + c4);
            ushort4 bv;
            bv.x = bfbits(av.x); bv.y = bfbits(av.y); bv.z = bfbits(av.z); bv.w = bfbits(av.w);
            *(ushort4*)&As[row][c4] = bv;
        }
#pragma unroll
        for (int pp = 0; pp < 4; ++pp) {          // B packed bf16 (128x64)
            int idx = pp * 256 + tid;             // 0..1023
            int row = idx >> 3, c8 = (idx & 7) * 8;
            *(uint4*)&Bs[row][c8] = *(const uint4*)(WT + (size_t)(wrow + row) * 1024 + k0 + c8);
        }
        __syncthreads();
#pragma unroll
        for (int ks = 0; ks < 64; ks += 32) {
            short8 af[4], bf[2];
#pragma unroll
            for (int mt = 0; mt < 4; ++mt)
                af[mt] = *(const short8*)&As[mt * 16 + l15][ks + quad * 8];
#pragma unroll
            for (int nt = 0; nt < 2; ++nt)
                bf[nt] = *(const short8*)&Bs[wave * 32 + nt * 16 + l15][ks + quad * 8];
#pragma unroll
            for (int mt = 0; mt < 4; ++mt)
#pragma unroll
                for (int nt = 0; nt < 2; ++nt)
                    acc[mt][nt] = MFMA16(af[mt], bf[nt], acc[mt][nt]);
        }
        __syncthreads();
    }
#pragma unroll
    for (int mt = 0; mt < 4; ++mt)
#pragma unroll
        for (int nt = 0; nt < 2; ++nt)
#pragma unroll
            for (int r = 0; r < 4; ++r) {
                int row = m0 + mt * 16 + quad * 4 + r;
                int col = n0 + wave * 32 + nt * 16 + l15;
                C[(size_t)row * N + col] = __float2bfloat16(acc[mt][nt][r]);
            }
}

// ---------------------------------------------------------------- output GEMM: out = att @ WoT^T
// 64x128 tiles, 512 blocks (2 blocks/CU). A bf16, C fp32. Same wave layout as gemm3.
__global__ __launch_bounds__(256) void gemm_out_kernel(const __hip_bfloat16* __restrict__ A,
                                                       const __hip_bfloat16* __restrict__ BT,
                                                       float* __restrict__ C) {
    __shared__ __align__(16) __hip_bfloat16 As[64][72];
    __shared__ __align__(16) __hip_bfloat16 Bs[128][72];
    int lin = blockIdx.x;                         // 0..511
    int n0 = ((lin >> 3) & 7) * 128;
    int mi = (lin & 7) + ((lin >> 6) << 3);       // 0..63
    int m0 = mi * 64;
    int tid = threadIdx.x;
    int wave = tid >> 6, lane = tid & 63, quad = lane >> 4, l15 = lane & 15;
    floatx4 acc[4][2];
#pragma unroll
    for (int mt = 0; mt < 4; ++mt)
#pragma unroll
        for (int nt = 0; nt < 2; ++nt) acc[mt][nt] = (floatx4){0.f, 0.f, 0.f, 0.f};

    for (int k0 = 0; k0 < 1024; k0 += 64) {
#pragma unroll
        for (int pp = 0; pp < 2; ++pp) {          // A bf16 (64x64)
            int idx = pp * 256 + tid;             // 0..511
            int row = idx >> 3, c8 = (idx & 7) * 8;
            *(uint4*)&As[row][c8] = *(const uint4*)(A + (size_t)(m0 + row) * 1024 + k0 + c8);
        }
#pragma unroll
        for (int pp = 0; pp < 4; ++pp) {          // B bf16 (128x64)
            int idx = pp * 256 + tid;             // 0..1023
            int row = idx >> 3, c8 = (idx & 7) * 8;
            *(uint4*)&Bs[row][c8] = *(const uint4*)(BT + (size_t)(n0 + row) * 1024 + k0 + c8);
        }
        __syncthreads();
#pragma unroll
        for (int ks = 0; ks < 64; ks += 32) {
            short8 af[4], bf[2];
#pragma unroll
            for (int mt = 0; mt < 4; ++mt)
                af[mt] = *(const short8*)&As[mt * 16 + l15][ks + quad * 8];
#pragma unroll
            for (int nt = 0; nt < 2; ++nt)
                bf[nt] = *(const short8*)&Bs[wave * 32 + nt * 16 + l15][ks + quad * 8];
#pragma unroll
            for (int mt = 0; mt < 4; ++mt)
#pragma unroll
                for (int nt = 0; nt < 2; ++nt)
                    acc[mt][nt] = MFMA16(af[mt], bf[nt], acc[mt][nt]);
        }
        __syncthreads();
    }
#pragma unroll
    for (int mt = 0; mt < 4; ++mt)
#pragma unroll
        for (int nt = 0; nt < 2; ++nt)
#pragma unroll
            for (int r = 0; r < 4; ++r) {
                int row = m0 + mt * 16 + quad * 4 + r;
                int col = n0 + wave * 32 + nt * 16 + l15;
                C[(size_t)row * 1024 + col] = acc[mt][nt][r];
            }
}

// ---------------------------------------------------------------- fused combine(+RoPE) + V-transpose
// R17 (= R14's version, now isolated): block = 8 tokens -> 512 blocks (2 blocks/CU,
// was 1). P loads vectorized uint4 (range boundaries 96/480 and 32/160 are %8==0,
// so chunks never straddle a split). qh folds log2(e)/768; vh folds 0.5.
// Padding cols (Pq 480.., Pk/Pv 160..) SKIPPED.
__global__ __launch_bounds__(256) void combine_vt_kernel(const __hip_bfloat16* __restrict__ Pq,
                                                         const __hip_bfloat16* __restrict__ Pk,
                                                         const __hip_bfloat16* __restrict__ Pv,
                                                         __hip_bfloat16* __restrict__ qh,
                                                         __hip_bfloat16* __restrict__ kh,
                                                         __hip_bfloat16* __restrict__ vT) {
    __shared__ __align__(16) __hip_bfloat16 LAq[8][96];
    __shared__ __align__(16) __hip_bfloat16 LAk[8][32];
    __shared__ __align__(16) __hip_bfloat16 LAv[8][32];
    __shared__ __align__(16) __hip_bfloat16 LBq[8][6][72];
    __shared__ __align__(16) __hip_bfloat16 LBk[8][2][72];
    __shared__ __align__(16) __hip_bfloat16 LBv[8][2][72];
    int tid = threadIdx.x;
    int token0 = blockIdx.x * 8;
    int b = token0 >> 11, s0 = token0 & 2047, bh0 = b * 16;

    // Pq: 8 tokens x 64 uint4-chunks = 512 chunks, 2 per thread
#pragma unroll
    for (int p = 0; p < 2; ++p) {
        int i = p * 256 + tid;              // 0..511
        int s = i >> 6, c8 = (i & 63) * 8;
        uint4 val = *(const uint4*)(Pq + (size_t)(token0 + s) * 512 + c8);
        if (c8 < 96) *(uint4*)&LAq[s][c8] = val;
        else if (c8 < 480) *(uint4*)&LBq[s][(c8 - 96) >> 6][(c8 - 96) & 63] = val;
    }
    // Pk/Pv: 8 tokens x 32 chunks = 256 chunks, 1 per thread
    {
        int s = tid >> 5, c8 = (tid & 31) * 8;
        uint4 vk = *(const uint4*)(Pk + (size_t)(token0 + s) * 256 + c8);
        uint4 vv = *(const uint4*)(Pv + (size_t)(token0 + s) * 256 + c8);
        if (c8 < 32) { *(uint4*)&LAk[s][c8] = vk; *(uint4*)&LAv[s][c8] = vv; }
        else if (c8 < 160) {
            *(uint4*)&LBk[s][(c8 - 32) >> 6][(c8 - 32) & 63] = vk;
            *(uint4*)&LBv[s][(c8 - 32) >> 6][(c8 - 32) & 63] = vv;
        }
    }
    __syncthreads();
    // RoPE on Bq (6 rows) + Bk (2 rows): 8 s x 8 rows x 32 pairs = 2048, 8 per thread
#pragma unroll
    for (int p = 0; p < 8; ++p) {
        int i = p * 256 + tid;
        int s = i >> 8, rr = (i >> 5) & 7, d = i & 31;
        float inv = __expf(-(float)d * 0.28782313662425576f);   // ln(10000)/32
        float rev = (float)(s0 + s) * inv * 0.15915494309189535f;
        rev -= floorf(rev);
        float sn = __builtin_amdgcn_sinf(rev);
        float cs = __builtin_amdgcn_cosf(rev);
        if (rr < 6) {
            float x1 = b2f(*(short*)&LBq[s][rr][d]), x2 = b2f(*(short*)&LBq[s][rr][d + 32]);
            LBq[s][rr][d] = __float2bfloat16(x1 * cs + x2 * sn);
            LBq[s][rr][d + 32] = __float2bfloat16(-x1 * sn + x2 * cs);
        } else {
            int r2 = rr - 6;
            float x1 = b2f(*(short*)&LBk[s][r2][d]), x2 = b2f(*(short*)&LBk[s][r2][d + 32]);
            LBk[s][r2][d] = __float2bfloat16(x1 * cs + x2 * sn);
            LBk[s][r2][d + 32] = __float2bfloat16(-x1 * sn + x2 * cs);
        }
    }
    __syncthreads();
    const float QSCALE = 1.4426950408889634f / 768.0f;  // log2(e)/(QR*RANK*DK)
    // qh/kh: thread = (s = tid>>5, h = (tid>>1)&15, dhalf = tid&1); 32 d's each
    {
        int s = tid >> 5, h = (tid >> 1) & 15, dh = tid & 1;
        float aq[6], ak0, ak1;
#pragma unroll
        for (int r = 0; r < 6; ++r) aq[r] = b2f(*(short*)&LAq[s][h * 6 + r]);
        ak0 = b2f(*(short*)&LAk[s][h * 2]);
        ak1 = b2f(*(short*)&LAk[s][h * 2 + 1]);
        size_t obase = ((size_t)(bh0 + h) * 2048 + s0 + s) * 64;
#pragma unroll
        for (int dq = 0; dq < 4; ++dq) {
            int dc = dh * 32 + dq * 8;
            float accq[8] = {0, 0, 0, 0, 0, 0, 0, 0};
#pragma unroll
            for (int r = 0; r < 6; ++r) {
                short8 bq = *(const short8*)&LBq[s][r][dc];
#pragma unroll
                for (int e = 0; e < 8; ++e) accq[e] += aq[r] * b2f(bq[e]);
            }
            short8 bk0 = *(const short8*)&LBk[s][0][dc];
            short8 bk1 = *(const short8*)&LBk[s][1][dc];
            ushort outq[8], outk[8];
#pragma unroll
            for (int e = 0; e < 8; ++e) {
                outq[e] = bfbits(accq[e] * QSCALE);
                outk[e] = bfbits(ak0 * b2f(bk0[e]) + ak1 * b2f(bk1[e]));
            }
            *(uint4*)((__hip_bfloat16*)qh + obase + dc) = *(uint4*)outq;
            *(uint4*)((__hip_bfloat16*)kh + obase + dc) = *(uint4*)outk;
        }
    }
    // vT: thread = (s = tid&7, dg = tid>>3); writes vT[bh][d][s0+s], d = dg*2+dd
    {
        int s = tid & 7, dg = tid >> 3;     // dg 0..31
#pragma unroll
        for (int h = 0; h < 16; ++h) {
            float a0 = b2f(*(short*)&LAv[s][h * 2]) * 0.5f;
            float a1 = b2f(*(short*)&LAv[s][h * 2 + 1]) * 0.5f;
#pragma unroll
            for (int dd = 0; dd < 2; ++dd) {
                int d = dg * 2 + dd;
                float val = a0 * b2f(*(short*)&LBv[s][0][d]) + a1 * b2f(*(short*)&LBv[s][1][d]);
                vT[((size_t)(bh0 + h) * 64 + d) * 2048 + s0 + s] = __float2bfloat16(val);
            }
        }
    }
}

// ---------------------------------------------------------------- causal flash attention (R13 best: 43.6us)
// 512 blocks x 512 threads (8 waves). Split-K wave groups: waves 0-3 (grp 0) compute
// even k-tiles from LDS buf0, waves 4-7 (grp 1) odd k-tiles from buf1; within a group,
// wv = wave&3 owns q-strip wv*16. Static-max softmax => O/rs are pure k-sums, so group
// partials add exactly (lane-aligned) via LDS at pass end. Tiles staged in PAIRS:
// 2 barriers per 2 tiles. T14 prefetch (issue pair p+1 after post-write barrier).
// T5: s_setprio(1) around the MFMA clusters (groups run phase-shifted -> arbitrable).
// 2 complementary passes (qi = 31-t then t): uniform 17 pairs per block.
// grid (32,16) linearized -> XCD-affine bh (K/V ~2MB per XCD L2).
__global__ __launch_bounds__(512) void flash_kernel(const __hip_bfloat16* __restrict__ qh,
                                                    const __hip_bfloat16* __restrict__ kh,
                                                    const __hip_bfloat16* __restrict__ vT,
                                                    __hip_bfloat16* __restrict__ att) {
    int lin = blockIdx.x + (blockIdx.y << 5);           // 0..511
    int bh = ((lin & 7) << 2) | ((lin >> 3) & 3);       // XCD-affine head mapping
    int tpair = lin >> 5;                               // 0..15
    int tid = threadIdx.x;
    int wave = tid >> 6, lane = tid & 63, quad = lane >> 4, l15 = lane & 15;
    int grp = wave >> 2, wv = wave & 3;
    __shared__ __align__(16) __hip_bfloat16 Ks[2][64][72];    // K[buf][kidx][d]
    __shared__ __align__(16) __hip_bfloat16 Vts[2][64][72];   // V^T[buf][d][kidx]
    float* cb = (float*)&Ks[0][0][0];   // combine buffer: 4*64*17 f32 = 17408B <= 18432B

    int row = tid >> 3, col = (tid & 7) * 8;            // staging: 512 thr cover 64x64 x4 arrays
    const size_t khb = (size_t)bh * 2048 * 64;
    const size_t vtb = (size_t)bh * 64 * 2048;
    uint4 sk0, sk1, sv0, sv1;
#define FL_ISSUE(P)                                                                  \
    {                                                                                \
        int k0_ = (P) * 128;                                                         \
        sk0 = *(const uint4*)(kh + khb + (size_t)(k0_ + row) * 64 + col);            \
        sk1 = *(const uint4*)(kh + khb + (size_t)(k0_ + 64 + row) * 64 + col);       \
        sv0 = *(const uint4*)(vT + vtb + (size_t)row * 2048 + k0_ + col);            \
        sv1 = *(const uint4*)(vT + vtb + (size_t)row * 2048 + k0_ + 64 + col);       \
    }

    for (int pass = 0; pass < 2; ++pass) {
        int qi = pass ? tpair : (31 - tpair);           // heavy pass first
        int q0 = qi * 64;
        int npairs = (qi + 2) >> 1;                     // ceil((qi+1)/2)
        const __hip_bfloat16* qrow =
            qh + ((size_t)bh * 2048 + q0 + wv * 16 + l15) * 64 + quad * 8;
        short8 aq0 = *(const short8*)(qrow);
        short8 aq1 = *(const short8*)(qrow + 32);

        floatx4 o[4];
#pragma unroll
        for (int nt = 0; nt < 4; ++nt) o[nt] = (floatx4){0.f, 0.f, 0.f, 0.f};
        float rs = 0.f;                 // scalar partial row-sum for q = wv*16 + l15
        int qloc = wv * 16 + l15;

        FL_ISSUE(0);
        for (int p = 0; p < npairs; ++p) {
            __syncthreads();            // all waves done reading previous buffers / cb
            *(uint4*)&Ks[0][row][col] = sk0;
            *(uint4*)&Ks[1][row][col] = sk1;
            *(uint4*)&Vts[0][row][col] = sv0;
            *(uint4*)&Vts[1][row][col] = sv1;
            __syncthreads();
            if (p + 1 < npairs) FL_ISSUE(p + 1);   // prefetch next pair during compute

            int mytile = 2 * p + grp;
            if (mytile <= qi) {         // wave-uniform predicate
                // S^T = K @ Q^T : lane holds S^T[k = nt*16+quad*4+r][q = l15]
                floatx4 s[4];
#pragma unroll
                for (int nt = 0; nt < 4; ++nt) s[nt] = (floatx4){0.f, 0.f, 0.f, 0.f};
                __builtin_amdgcn_s_setprio(1);
#pragma unroll
                for (int nt = 0; nt < 4; ++nt) {
                    short8 bk0 = *(const short8*)&Ks[grp][nt * 16 + l15][quad * 8];
                    short8 bk1 = *(const short8*)&Ks[grp][nt * 16 + l15][32 + quad * 8];
                    s[nt] = MFMA16(bk0, aq0, s[nt]);
                    s[nt] = MFMA16(bk1, aq1, s[nt]);
                }
                __builtin_amdgcn_s_setprio(0);
                if (mytile == qi) {  // causal mask on diagonal tile
#pragma unroll
                    for (int nt = 0; nt < 4; ++nt) {
                        int kbase = nt * 16 + quad * 4;
#pragma unroll
                        for (int r = 0; r < 4; ++r)
                            if (kbase + r > qloc) s[nt][r] = -__builtin_inff();
                    }
                }
                float pv[4][4];
#pragma unroll
                for (int nt = 0; nt < 4; ++nt)
#pragma unroll
                    for (int r = 0; r < 4; ++r) {
                        pv[nt][r] = exp2f(s[nt][r]);
                        rs += pv[nt][r];
                    }
                union { ushort u[8]; short8 v; } p0, p1;
#pragma unroll
                for (int r = 0; r < 4; ++r) {
                    p0.u[r]     = bfbits(pv[0][r]);
                    p0.u[4 + r] = bfbits(pv[1][r]);
                    p1.u[r]     = bfbits(pv[2][r]);
                    p1.u[4 + r] = bfbits(pv[3][r]);
                }
                // O^T += V^T @ P^T with slot-permuted V reads (4x b64 per d-block)
                __builtin_amdgcn_s_setprio(1);
#pragma unroll
                for (int nt = 0; nt < 4; ++nt) {
                    int vr = nt * 16 + l15;
                    union { ushort4 h[2]; short8 v; } x0, x1;
                    x0.h[0] = *(const ushort4*)&Vts[grp][vr][quad * 4];
                    x0.h[1] = *(const ushort4*)&Vts[grp][vr][16 + quad * 4];
                    x1.h[0] = *(const ushort4*)&Vts[grp][vr][32 + quad * 4];
                    x1.h[1] = *(const ushort4*)&Vts[grp][vr][48 + quad * 4];
                    o[nt] = MFMA16(x0.v, p0.v, o[nt]);
                    o[nt] = MFMA16(x1.v, p1.v, o[nt]);
                }
                __builtin_amdgcn_s_setprio(0);
            }
        }
        // cross-group combine: grp1 partials -> LDS, grp0 adds (lanes own same (q,d))
        __syncthreads();                // grp0's last compute done before cb overwrite
        int cbase = (wv * 64 + lane) * 17;
        if (grp == 1) {
#pragma unroll
            for (int nt = 0; nt < 4; ++nt)
#pragma unroll
                for (int r = 0; r < 4; ++r) cb[cbase + nt * 4 + r] = o[nt][r];
            cb[cbase + 16] = rs;
        }
        __syncthreads();
        if (grp == 0) {
#pragma unroll
            for (int nt = 0; nt < 4; ++nt)
#pragma unroll
                for (int r = 0; r < 4; ++r) o[nt][r] += cb[cbase + nt * 4 + r];
            rs += cb[cbase + 16];
            // full row-sum: reduce across the 4 quads holding q = l15
            rs += __shfl_xor(rs, 16, 64);
            rs += __shfl_xor(rs, 32, 64);
            float inv = 1.0f / rs;
            // epilogue: att[b][q][h*64+d], d = nt*16 + quad*4 + r -> 8B stores
            int b = bh >> 4, h = bh & 15;
            size_t obase = ((size_t)b * 2048 + q0 + wv * 16 + l15) * 1024 + h * 64 + quad * 4;
#pragma unroll
            for (int nt = 0; nt < 4; ++nt) {
                ushort ow[4];
#pragma unroll
                for (int r = 0; r < 4; ++r) ow[r] = bfbits(o[nt][r] * inv);
                *(ushort4*)((__hip_bfloat16*)att + obase + nt * 16) = *(ushort4*)ow;
            }
        }
    }
#undef FL_ISSUE
}

// ---------------------------------------------------------------- launch
extern "C" void kernel_launch(void* const* d_in, const int* in_sizes, int n_in,
                              void* d_out, int out_size, void* d_ws, size_t ws_size,
                              hipStream_t stream) {
    const float* q = (const float*)d_in[0];
    const float* k = (const float*)d_in[1];
    const float* v = (const float*)d_in[2];
    // d_in[3] = causal mask (ignored; computed analytically)
    const float* W_Aq = (const float*)d_in[4];
    const float* W_Ak = (const float*)d_in[5];
    const float* W_Av = (const float*)d_in[6];
    const float* W_Bq = (const float*)d_in[7];
    const float* W_Bk = (const float*)d_in[8];
    const float* W_Bv = (const float*)d_in[9];
    const float* Wo = (const float*)d_in[10];
    float* out = (float*)d_out;

    char* w = (char*)d_ws;
    __hip_bfloat16* qh  = (__hip_bfloat16*)(w + 0);          // [32][2048][64] 8.4 MB
    __hip_bfloat16* kh  = (__hip_bfloat16*)(w + 8388608);    // [32][2048][64]
    __hip_bfloat16* vT  = (__hip_bfloat16*)(w + 16777216);   // [32][64][2048]
    __hip_bfloat16* WT  = (__hip_bfloat16*)(w + 25165824);   // [2048][1024] packed bf16
    __hip_bfloat16* WoT = WT + (size_t)1024 * 1024;          // rows 1024..2047
    __hip_bfloat16* Pq  = (__hip_bfloat16*)(w + 29360128);   // [4096][512] bf16
    __hip_bfloat16* Pk  = (__hip_bfloat16*)(w + 33554432);   // [4096][256]
    __hip_bfloat16* Pv  = (__hip_bfloat16*)(w + 35651584);   // [4096][256]
    __hip_bfloat16* att = (__hip_bfloat16*)(w + 37748736);   // [4096][1024] bf16

    pack_wT_kernel<<<dim3(16, 32), 256, 0, stream>>>(W_Aq, W_Bq, W_Ak, W_Bk, W_Av, W_Bv, Wo, WT);
    gemm3_kernel<<<512, 256, 0, stream>>>(q, k, v, WT, Pq, Pk, Pv);
    combine_vt_kernel<<<512, 256, 0, stream>>>(Pq, Pk, Pv, qh, kh, vT);
    flash_kernel<<<dim3(32, 16), 512, 0, stream>>>(qh, kh, vT, att);
    gemm_out_kernel<<<512, 256, 0, stream>>>(att, WoT, out);
}